// Round 20
// baseline (621.528 us; speedup 1.0000x reference)
//
#include <hip/hip_runtime.h>
#include <hip/hip_bf16.h>
#include <math.h>

typedef __bf16 bf16_t;
typedef __bf16 bf16x8 __attribute__((ext_vector_type(8)));
typedef __bf16 bf16x4v __attribute__((ext_vector_type(4)));
typedef float  f32x4  __attribute__((ext_vector_type(4)));
typedef float  f32x16 __attribute__((ext_vector_type(16)));
typedef unsigned int u32x4 __attribute__((ext_vector_type(4)));

constexpr int CB = 4, CS = 2048, CH = 2048, CNH = 16, CHD = 128;
constexpr int CM = CB * CS;  // 8192 rows of x
constexpr float CSCALE = 0.08838834764831845f;  // 128^-0.5
constexpr float CL2E   = 1.4426950408889634f;
constexpr float CSC2   = CSCALE * CL2E;         // score -> log2 domain in one mul

// raw v_exp_f32 (2^x)
__device__ __forceinline__ float fexp2(float x) {
  float r;
  asm("v_exp_f32 %0, %1" : "=v"(r) : "v"(x));
  return r;
}

// async global->LDS, 16B per lane. LDS dest is wave-uniform base (+lane*16 by HW).
__device__ __forceinline__ void g2l16(const void* g, void* l) {
  __builtin_amdgcn_global_load_lds(
      (const __attribute__((address_space(1))) void*)g,
      (__attribute__((address_space(3))) void*)l, 16, 0, 0);
}

// ---------------- f32 -> bf16 conversion: all 5 tensors in ONE launch ----------------
__global__ __launch_bounds__(256) void cvt_all(const float* __restrict__ x,
                                               const float* __restrict__ Wq,
                                               const float* __restrict__ Wk,
                                               const float* __restrict__ Wv,
                                               const float* __restrict__ Wo,
                                               bf16_t* __restrict__ xb,
                                               bf16_t* __restrict__ wqb,
                                               bf16_t* __restrict__ wkb,
                                               bf16_t* __restrict__ wvb,
                                               bf16_t* __restrict__ wob) {
  constexpr int NX = CM * CH / 4;  // float4 units in x
  constexpr int NW = CH * CH / 4;  // float4 units per weight
  const int i = blockIdx.x * 256 + threadIdx.x;
  const float* src;
  bf16_t* dst;
  int off;
  if (i < NX) {
    src = x; dst = xb; off = i;
  } else {
    const int j = i - NX;
    const int sel = j / NW;
    off = j - sel * NW;
    src = (sel == 0) ? Wq : (sel == 1) ? Wk : (sel == 2) ? Wv : Wo;
    dst = (sel == 0) ? wqb : (sel == 1) ? wkb : (sel == 2) ? wvb : wob;
  }
  float4 v = reinterpret_cast<const float4*>(src)[off];
  bf16x4v o = {(bf16_t)v.x, (bf16_t)v.y, (bf16_t)v.z, (bf16_t)v.w};
  reinterpret_cast<bf16x4v*>(dst)[off] = o;
}

// ====== R20 qkv core: 256x256 BK=64, A staged in LDS (64KB dbuf), B DIRECT from L2 ======
// B operand (weights, row-major [N][K], 8MB L2-resident) is read per-lane in the
// MFMA-native pattern: Bm[(col0+n)*CH + kt*64 + kk*32 + (lane>>4)*8] — byte-identical
// to what the old LDS path produced (verified against rdB's involution).  LDS halves
// to 64KB -> 2 blocks/CU (cross-block overlap, m114).  Stage order A0,A2,A1,A3;
// counted vmcnt(2) at p1-end (lands A1,A3 of t) and p3-end (lands A0,A2 of t+1);
// 2 barriers/tile (cross-thread DMA visibility + buffer-swap guard).
__device__ __forceinline__ void gemmL2B_core(const bf16_t* __restrict__ A,
                                             const bf16_t* __restrict__ Bm,
                                             bf16_t (*As2)[4][64 * 64],
                                             int row0, int col0,
                                             f32x4 (&acc)[8][4]) {
  const int tid = threadIdx.x, lane = tid & 63, w = tid >> 6;
  const int wm = w >> 2, wn = w & 3;
  constexpr int NKT = CH / 64;  // 32 K-tiles
  const int rl = tid >> 3, ck = tid & 7;  // A-stage: row-local 0..63, chunk 0..7

  auto stA = [&](int buf, int kt, int q) {
    const int row = q * 64 + rl;
    g2l16(A + (size_t)(row0 + row) * CH + kt * 64 + ((ck ^ (row & 7)) << 3),
          &As2[buf][q][tid * 8]);
  };
  auto rdA = [&](int buf, int r, int c) -> bf16x8 {  // r: tile row 0..255
    return *(const bf16x8*)(&As2[buf][r >> 6][(r & 63) * 64 + ((c ^ (r & 7)) << 3)]);
  };

  // prologue: stage tile 0 (4 quarters), drain, barrier
#pragma unroll
  for (int q = 0; q < 4; ++q) stA(0, 0, q);
  asm volatile("s_waitcnt vmcnt(0)" ::: "memory");
  __builtin_amdgcn_s_barrier();
  __builtin_amdgcn_sched_barrier(0);

  const int ar0 = wm * 128 + (lane & 15);
  const int bn0 = col0 + wn * 64 + (lane & 15);  // B col for nf=0
  const int bk0 = (lane >> 4) * 8;
  const int chi = lane >> 4;  // A K-slice kk -> chunk kk*4+chi
  const int qorder[4] = {0, 2, 1, 3};

  for (int t = 0; t < NKT; ++t) {
    const int buf = t & 1, nbuf = buf ^ 1;
    const bool pf = (t + 1 < NKT);

    // B fragments direct from L2 (batched, 8 loads)
    bf16x8 bb[4][2];
#pragma unroll
    for (int nf = 0; nf < 4; ++nf)
#pragma unroll
      for (int kk = 0; kk < 2; ++kk)
        bb[nf][kk] = *(const bf16x8*)(Bm + (size_t)(bn0 + nf * 16) * CH +
                                      t * 64 + kk * 32 + bk0);

#pragma unroll
    for (int p = 0; p < 4; ++p) {
      if (pf) stA(nbuf, t + 1, qorder[p]);

      bf16x8 aa[2][2];
#pragma unroll
      for (int i = 0; i < 2; ++i)
#pragma unroll
        for (int kk = 0; kk < 2; ++kk)
          aa[i][kk] = rdA(buf, ar0 + (2 * p + i) * 16, kk * 4 + chi);

      __builtin_amdgcn_s_setprio(1);
#pragma unroll
      for (int i = 0; i < 2; ++i)
#pragma unroll
        for (int nf = 0; nf < 4; ++nf)
#pragma unroll
          for (int kk = 0; kk < 2; ++kk)
            acc[2 * p + i][nf] = __builtin_amdgcn_mfma_f32_16x16x32_bf16(
                aa[i][kk], bb[nf][kk], acc[2 * p + i][nf], 0, 0, 0);
      __builtin_amdgcn_s_setprio(0);

      if (p == 1) {  // A1,A3 of tile t must be landed before p2 reads them
        if (pf) { asm volatile("s_waitcnt vmcnt(2)" ::: "memory"); }
        else    { asm volatile("s_waitcnt vmcnt(0)" ::: "memory"); }
        __builtin_amdgcn_s_barrier();
        __builtin_amdgcn_sched_barrier(0);
      }
      if (p == 3) {  // boundary: A0,A2 of t+1 landed; also guards buffer swap
        if (pf) { asm volatile("s_waitcnt vmcnt(2)" ::: "memory"); }
        __builtin_amdgcn_s_barrier();
        __builtin_amdgcn_sched_barrier(0);
      }
    }
  }
}

// ---------------- QKV projection (grid.z selects Q/K/V; R20: L2-direct B) ----------------
// Epilogues: 2 half-passes through 64KB LDS ([128][256] bf16, ch ^ (rl&31) swizzle).
__global__ __launch_bounds__(512, 1) void qkv_gemm(const bf16_t* __restrict__ xb,
                                                   const bf16_t* __restrict__ wqb,
                                                   const bf16_t* __restrict__ wkb,
                                                   const bf16_t* __restrict__ wvb,
                                                   bf16_t* __restrict__ qraw,
                                                   bf16_t* __restrict__ knat,
                                                   bf16_t* __restrict__ vt2,
                                                   float* __restrict__ vout) {
  __shared__ __align__(16) bf16_t As2[2][4][64 * 64];  // 64KB
  const int z = blockIdx.z;
  const bf16_t* Bm = (z == 0) ? wqb : ((z == 1) ? wkb : wvb);
  const int row0 = blockIdx.x * 256, col0 = blockIdx.y * 256;
  f32x4 acc[8][4] = {};
  gemmL2B_core(xb, Bm, As2, row0, col0, acc);

  const int tid = threadIdx.x, lane = tid & 63, w = tid >> 6;
  const int wm = w >> 2, wn = w & 3;
  bf16_t* L = &As2[0][0][0];  // [128][256] bf16 per half-pass

  if (z == 2) {
    // V^T native stores directly from acc (8B-contiguous)
#pragma unroll
    for (int i = 0; i < 8; ++i)
#pragma unroll
      for (int j = 0; j < 4; ++j) {
        const int gr0 = row0 + wm * 128 + i * 16 + (lane >> 4) * 4;
        const int gc = col0 + wn * 64 + j * 16 + (lane & 15);
        const int b = gr0 >> 11, s0 = gr0 & (CS - 1);
        const int nh = gc >> 7, hd = gc & (CHD - 1);
        const int bh = b * CNH + nh;
        bf16x4v pv = {(bf16_t)acc[i][j][0], (bf16_t)acc[i][j][1],
                      (bf16_t)acc[i][j][2], (bf16_t)acc[i][j][3]};
        *(bf16x4v*)(vt2 + (((size_t)bh * (CS / 16) + (s0 >> 4)) * CHD + hd) * 16 +
                    (s0 & 15)) = pv;
      }
  }

  // two half-passes: wave-half wm==half stages its 128 rows, everyone emits
#pragma unroll
  for (int half = 0; half < 2; ++half) {
    __syncthreads();  // prior-pass reads (or core reads) done before overwrite
    if (wm == half) {
#pragma unroll
      for (int i = 0; i < 8; ++i)
#pragma unroll
        for (int j = 0; j < 4; ++j) {
          const int col = wn * 64 + j * 16 + (lane & 15);
#pragma unroll
          for (int r = 0; r < 4; ++r) {
            const int rl = i * 16 + (lane >> 4) * 4 + r;  // 0..127
            L[rl * 256 + (((col >> 3) ^ (rl & 31)) << 3) + (col & 7)] =
                (bf16_t)acc[i][j][r];
          }
        }
    }
    __syncthreads();

    if (z == 0) {
      // Q row-major (pre-RoPE): coalesced 16B stores
#pragma unroll
      for (int k = 0; k < 8; ++k) {
        const int u = k * 512 + tid;
        const int rl = u >> 5, ch = u & 31;
        bf16x8 v = *(const bf16x8*)&L[rl * 256 + ((ch ^ (rl & 31)) << 3)];
        const int gr = row0 + half * 128 + rl, gc = col0 + ch * 8;
        const int b = gr >> 11, s = gr & (CS - 1), nh = gc >> 7, hd = gc & (CHD - 1);
        *(bf16x8*)&qraw[((size_t)(b * CNH + nh) * CS + s) * CHD + hd] = v;
      }
    } else if (z == 2) {
      // vout f32: coalesced 32B per lane
#pragma unroll
      for (int k = 0; k < 8; ++k) {
        const int u = k * 512 + tid;
        const int rl = u >> 5, ch = u & 31;
        bf16x8 v = *(const bf16x8*)&L[rl * 256 + ((ch ^ (rl & 31)) << 3)];
        const int gr = row0 + half * 128 + rl, gc = col0 + ch * 8;
        const int b = gr >> 11, s = gr & (CS - 1), nh = gc >> 7, hd = gc & (CHD - 1);
        float o[8];
#pragma unroll
        for (int e = 0; e < 8; ++e) o[e] = (float)v[e];
        float* vp = vout + ((size_t)(b * CNH + nh) * CS + s) * CHD + hd;
        *(float4*)(vp)     = *(float4*)(o);
        *(float4*)(vp + 4) = *(float4*)(o + 4);
      }
    } else {
      // K native [bh][pan][s][16] PRE-RoPE: s-major lanes -> 16B stores
#pragma unroll
      for (int k = 0; k < 8; ++k) {
        const int u = k * 512 + tid;
        const int sl = u & 127, cc = u >> 7;
        bf16x8 v = *(const bf16x8*)&L[sl * 256 + ((cc ^ (sl & 31)) << 3)];
        const int gr = row0 + half * 128 + sl, gc = col0 + cc * 8;
        const int b = gr >> 11, sg = gr & (CS - 1), nh = gc >> 7, hd = gc & (CHD - 1);
        const int pan = hd >> 4, hf = (hd >> 3) & 1;
        *(bf16x8*)&knat[(((size_t)(b * CNH + nh) * 8 + pan) * CS + sg) * 16 +
                        hf * 8] = v;
      }
    }
  }
}

// ================= old 256x256 core (A+B LDS) — kept for y_gemm =================
__device__ __forceinline__ void gemm256sq_core(const bf16_t* __restrict__ A,
                                               const bf16_t* __restrict__ Bm,
                                               bf16_t (*As2)[4][64 * 64],
                                               bf16_t (*Bs2)[4][64 * 64],
                                               int row0, int col0,
                                               f32x4 (&acc)[8][4]) {
  const int tid = threadIdx.x, lane = tid & 63, w = tid >> 6;
  const int wm = w >> 2, wn = w & 3;
  constexpr int NKT = CH / 64;  // 32 K-tiles
  const int id = w * 64 + lane;           // 0..511
  const int rl = id >> 3, ck = id & 7;    // row-local 0..63, chunk 0..7

  auto stA = [&](int buf, int kt, int q) {
    const int row = q * 64 + rl;
    g2l16(A + (size_t)(row0 + row) * CH + kt * 64 + ((ck ^ (row & 7)) << 3),
          &As2[buf][q][id * 8]);
  };
  auto stB = [&](int buf, int kt, int q) {
    const int row = q * 64 + rl;
    g2l16(Bm + (size_t)(col0 + row) * CH + kt * 64 + ((ck ^ (row & 7)) << 3),
          &Bs2[buf][q][id * 8]);
  };
  auto rdA = [&](int buf, int r, int c) -> bf16x8 {  // r: tile row 0..255
    return *(const bf16x8*)(&As2[buf][r >> 6][(r & 63) * 64 + ((c ^ (r & 7)) << 3)]);
  };
  auto rdB = [&](int buf, int r, int c) -> bf16x8 {
    return *(const bf16x8*)(&Bs2[buf][r >> 6][(r & 63) * 64 + ((c ^ (r & 7)) << 3)]);
  };

  // prologue: stage all 8 quarters of tile 0, drain, barrier
#pragma unroll
  for (int q = 0; q < 4; ++q) stB(0, 0, q);
#pragma unroll
  for (int q = 0; q < 4; ++q) stA(0, 0, q);
  asm volatile("s_waitcnt vmcnt(0)" ::: "memory");
  __builtin_amdgcn_s_barrier();
  __builtin_amdgcn_sched_barrier(0);

  const int ar0 = wm * 128 + (lane & 15);
  const int br0 = wn * 64 + (lane & 15);
  const int chi = lane >> 4;  // K-slice kk -> chunk kk*4+chi

  for (int t = 0; t < NKT; ++t) {
    const int buf = t & 1, nbuf = buf ^ 1;
    const bool pf = (t + 1 < NKT);
    bf16x8 bb[4][2], aa[2][2];

#pragma unroll
    for (int p = 0; p < 4; ++p) {
      if (p == 0) {
#pragma unroll
        for (int nf = 0; nf < 4; ++nf)
#pragma unroll
          for (int kk = 0; kk < 2; ++kk)
            bb[nf][kk] = rdB(buf, br0 + nf * 16, kk * 4 + chi);
      }
#pragma unroll
      for (int i = 0; i < 2; ++i)
#pragma unroll
        for (int kk = 0; kk < 2; ++kk)
          aa[i][kk] = rdA(buf, ar0 + (2 * p + i) * 16, kk * 4 + chi);

      if (pf) {
        if (p == 0) { stB(nbuf, t + 1, 0); stB(nbuf, t + 1, 1); }
        if (p == 1) { stA(nbuf, t + 1, 0); stA(nbuf, t + 1, 2); }
        if (p == 2) { stB(nbuf, t + 1, 2); stB(nbuf, t + 1, 3); }
        if (p == 3) { stA(nbuf, t + 1, 1); stA(nbuf, t + 1, 3); }
      }

      __builtin_amdgcn_s_barrier();
      asm volatile("s_waitcnt lgkmcnt(0)" ::: "memory");
      __builtin_amdgcn_sched_barrier(0);
      __builtin_amdgcn_s_setprio(1);
#pragma unroll
      for (int i = 0; i < 2; ++i)
#pragma unroll
        for (int nf = 0; nf < 4; ++nf)
#pragma unroll
          for (int kk = 0; kk < 2; ++kk)
            acc[2 * p + i][nf] = __builtin_amdgcn_mfma_f32_16x16x32_bf16(
                aa[i][kk], bb[nf][kk], acc[2 * p + i][nf], 0, 0, 0);
      __builtin_amdgcn_s_setprio(0);

      if (p == 1) {
        if (pf) { asm volatile("s_waitcnt vmcnt(4)" ::: "memory"); }
        else    { asm volatile("s_waitcnt vmcnt(0)" ::: "memory"); }
      }
      if (p == 3 && pf) { asm volatile("s_waitcnt vmcnt(2)" ::: "memory"); }
      __builtin_amdgcn_s_barrier();
      __builtin_amdgcn_sched_barrier(0);
    }
  }
}

// ---------------- output projection y = ob * Wo^T (R14 version, unchanged) ----------------
__global__ __launch_bounds__(512, 1) void y_gemm(const bf16_t* __restrict__ ob,
                                                 const bf16_t* __restrict__ wob,
                                                 float* __restrict__ yout) {
  __shared__ __align__(16) bf16_t LSD[2][2][4][64 * 64];  // 128KB
  const int row0 = blockIdx.x * 256, col0 = blockIdx.y * 256;
  f32x4 acc[8][4] = {};
  gemm256sq_core(ob, wob, LSD[0], LSD[1], row0, col0, acc);
  const int tid = threadIdx.x, lane = tid & 63, w = tid >> 6;
  const int wm = w >> 2, wn = w & 3;
  float* Lf = (float*)&LSD[0][0][0][0];  // [128][256] f32 per pass

#pragma unroll
  for (int half = 0; half < 2; ++half) {
    if (wm == half) {
#pragma unroll
      for (int i = 0; i < 8; ++i)
#pragma unroll
        for (int j = 0; j < 4; ++j) {
          const int col = wn * 64 + j * 16 + (lane & 15);
#pragma unroll
          for (int r = 0; r < 4; ++r) {
            const int rl = i * 16 + (lane >> 4) * 4 + r;  // row within half
            Lf[rl * 256 + col] = acc[i][j][r];
          }
        }
    }
    __syncthreads();
#pragma unroll
    for (int k = 0; k < 16; ++k) {
      const int u = k * 512 + tid;
      const int rl = u >> 6, ch = u & 63;
      float4 v = *(const float4*)&Lf[rl * 256 + ch * 4];
      const int gr = row0 + half * 128 + rl, gc = col0 + ch * 4;
      *(float4*)&yout[(size_t)gr * CH + gc] = v;
    }
    __syncthreads();
  }
}

// ---------------- RoPE: K only (native layout, in place) + f32 kout ----------------
__global__ __launch_bounds__(256) void rope_k(bf16_t* __restrict__ knat,
                                              const float* __restrict__ cosd,
                                              const float* __restrict__ sind,
                                              float* __restrict__ kout) {
  const int gid = blockIdx.x * 256 + threadIdx.x;  // B*NH*S*8 units
  const int row = gid >> 3, sub = gid & 7;
  const int pan = sub >> 1, hf = (sub & 1) * 8;  // hd1 = pan*16+hf+e (<64)
  const int bh = row >> 11, s = row & (CS - 1);
  const int d0 = pan * 16 + hf;
  bf16_t* k1 = knat + (((size_t)bh * 8 + pan) * CS + s) * 16 + hf;
  bf16_t* k2 = knat + (((size_t)bh * 8 + pan + 4) * CS + s) * 16 + hf;
  bf16x8 v1 = *(bf16x8*)k1;
  bf16x8 v2 = *(bf16x8*)k2;
  float c[8], sn[8];
  *(float4*)(c)      = *(const float4*)(cosd + s * CHD + d0);
  *(float4*)(c + 4)  = *(const float4*)(cosd + s * CHD + d0 + 4);
  *(float4*)(sn)     = *(const float4*)(sind + s * CHD + d0);
  *(float4*)(sn + 4) = *(const float4*)(sind + s * CHD + d0 + 4);
  float f1[8], f2[8];
  bf16x8 o1, o2;
#pragma unroll
  for (int i = 0; i < 8; ++i) {
    const float x1 = (float)v1[i], x2 = (float)v2[i];
    f1[i] = x1 * c[i] - x2 * sn[i];
    f2[i] = x2 * c[i] + x1 * sn[i];
    o1[i] = (bf16_t)f1[i];
    o2[i] = (bf16_t)f2[i];
  }
  *(bf16x8*)k1 = o1;
  *(bf16x8*)k2 = o2;
  const size_t kb = (size_t)row * CHD + d0;
  *(float4*)(kout + kb)          = *(float4*)(f1);
  *(float4*)(kout + kb + 4)      = *(float4*)(f1 + 4);
  *(float4*)(kout + kb + 64)     = *(float4*)(f2);
  *(float4*)(kout + kb + 64 + 4) = *(float4*)(f2 + 4);
}

// ---------------- flash attention (R17 version — best measured) ----------------
__global__ __launch_bounds__(128, 3) void attn_kernel(const bf16_t* __restrict__ qb,
                                                      const bf16_t* __restrict__ kn,
                                                      const bf16_t* __restrict__ v2,
                                                      const float* __restrict__ cosd,
                                                      const float* __restrict__ sind,
                                                      bf16_t* __restrict__ ob) {
  __shared__ float Os[32][129];
  __shared__ float Ms[32], Ls[32];
  const int tid = threadIdx.x, lane = tid & 63, wh = tid >> 6;  // wh = kv-half
  const int hi = lane >> 5, l31 = lane & 31;

  const int swz = (blockIdx.x & 7) * 512 + (blockIdx.x >> 3);
  const int bh = swz >> 6;
  const int qt = 63 - (swz & 63);

  const int b = bh >> 4, nh = bh & (CNH - 1);
  const bf16_t* kbase = kn + (size_t)bh * 8 * CS * 16;           // [8][S][16]
  const bf16_t* vbase = v2 + (size_t)bh * (CS / 16) * CHD * 16;  // [S/16][hd][16]
  const int qw0 = qt * 32;
  const int qrow = qw0 + l31;

  // Q load + fused RoPE: frag pair (ks, ks+4) is the (d, d+64) rotation pair
  bf16x8 bq[8];
  {
    const bf16_t* qp = qb + ((size_t)bh * CS + qrow) * CHD + hi * 8;
    bf16x8 raw[8];
#pragma unroll
    for (int ks = 0; ks < 8; ++ks) raw[ks] = *(const bf16x8*)(qp + ks * 16);
#pragma unroll
    for (int p = 0; p < 4; ++p) {
      const int d0 = p * 16 + hi * 8;
      float cc[8], ss[8];
      *(float4*)(cc)     = *(const float4*)(cosd + (size_t)qrow * CHD + d0);
      *(float4*)(cc + 4) = *(const float4*)(cosd + (size_t)qrow * CHD + d0 + 4);
      *(float4*)(ss)     = *(const float4*)(sind + (size_t)qrow * CHD + d0);
      *(float4*)(ss + 4) = *(const float4*)(sind + (size_t)qrow * CHD + d0 + 4);
#pragma unroll
      for (int e = 0; e < 8; ++e) {
        const float x1 = (float)raw[p][e], x2 = (float)raw[p + 4][e];
        bq[p][e]     = (bf16_t)(x1 * cc[e] - x2 * ss[e]);
        bq[p + 4][e] = (bf16_t)(x2 * cc[e] + x1 * ss[e]);
      }
    }
  }

  float m_ = -INFINITY, l_ = 0.f;
  f32x16 o_[4] = {};  // O^T: hd = 32*hb + 4*hi + (r&3) + 8*(r>>2), q = l31

  const int nt = (qt >> 1) + 1;
  for (int kt = wh; kt < nt; kt += 2) {
    const int kvb = kt * 64;

    // QK^T swapped, K consumed in 2 batches of 8 loads (liveness 32 VGPR)
    f32x16 st[2] = {};
#pragma unroll
    for (int kb2 = 0; kb2 < 2; ++kb2) {
      bf16x8 ak[8];
      const bf16_t* kr = kbase + (size_t)(kvb + kb2 * 32 + l31) * 16 + hi * 8;
#pragma unroll
      for (int ks = 0; ks < 8; ++ks)
        ak[ks] = *(const bf16x8*)(kr + (size_t)ks * CS * 16);
#pragma unroll
      for (int ks = 0; ks < 8; ++ks)
        st[kb2] = __builtin_amdgcn_mfma_f32_32x32x16_bf16(ak[ks], bq[ks],
                                                          st[kb2], 0, 0, 0);
    }

    // scale (log2 domain) + causal mask on diagonal-crossing tiles
    const bool anymask = (kvb + 63) > qw0;
#pragma unroll
    for (int blk = 0; blk < 2; ++blk)
#pragma unroll
      for (int r = 0; r < 16; ++r) {
        float xv = st[blk][r] * CSC2;
        if (anymask) {
          const int kv = kvb + blk * 32 + 4 * hi + (r & 3) + 8 * (r >> 2);
          if (kv > qrow) xv = -INFINITY;
        }
        st[blk][r] = xv;
      }

    // row max: in-register chain + one cross-half exchange
    float tmax = st[0][0];
#pragma unroll
    for (int r = 1; r < 16; ++r) tmax = fmaxf(tmax, st[0][r]);
#pragma unroll
    for (int r = 0; r < 16; ++r) tmax = fmaxf(tmax, st[1][r]);
    tmax = fmaxf(tmax, __shfl_xor(tmax, 32, 64));

    // defer-max (T13), log2 domain: P bounded by 2^8
    if (__any(tmax - m_ > 8.0f)) {
      const float mn = fmaxf(m_, tmax);
      const float corr = fexp2(m_ - mn);
      m_ = mn;
      l_ *= corr;
#pragma unroll
      for (int hb = 0; hb < 4; ++hb) o_[hb] *= corr;
    }

    // P = exp2(x - m) in place, row sum
    float psum = 0.f;
#pragma unroll
    for (int blk = 0; blk < 2; ++blk)
#pragma unroll
      for (int r = 0; r < 16; ++r) {
        const float pv = fexp2(st[blk][r] - m_);
        st[blk][r] = pv;
        psum += pv;
      }
    psum += __shfl_xor(psum, 32, 64);
    l_ += psum;

    // preload V hb=0 (latency hides under pb conversion)
    bf16x8 av[2][4];
    {
      const bf16_t* vr = vbase + ((size_t)(kvb >> 4) * CHD + l31) * 16 + hi * 8;
#pragma unroll
      for (int ks = 0; ks < 4; ++ks)
        av[0][ks] = *(const bf16x8*)(vr + (size_t)ks * CHD * 16);
    }

    // P^T B-frags: 16 cvt_pk + 8 permlane32_swap (R9-verified pairing)
    bf16x8 pb[4];
#pragma unroll
    for (int ks = 0; ks < 4; ++ks) {
      const int blk = ks >> 1, r0 = (ks & 1) * 8;
      unsigned pw0, pw1, pw2, pw3;
      asm("v_cvt_pk_bf16_f32 %0, %1, %2" : "=v"(pw0) : "v"(st[blk][r0 + 0]), "v"(st[blk][r0 + 1]));
      asm("v_cvt_pk_bf16_f32 %0, %1, %2" : "=v"(pw2) : "v"(st[blk][r0 + 4]), "v"(st[blk][r0 + 5]));
      asm("v_cvt_pk_bf16_f32 %0, %1, %2" : "=v"(pw1) : "v"(st[blk][r0 + 2]), "v"(st[blk][r0 + 3]));
      asm("v_cvt_pk_bf16_f32 %0, %1, %2" : "=v"(pw3) : "v"(st[blk][r0 + 6]), "v"(st[blk][r0 + 7]));
      asm("v_permlane32_swap_b32 %0, %1" : "+v"(pw0), "+v"(pw2));
      asm("v_permlane32_swap_b32 %0, %1" : "+v"(pw1), "+v"(pw3));
      u32x4 pk = {pw0, pw1, pw2, pw3};
      pb[ks] = *reinterpret_cast<bf16x8*>(&pk);
    }

    // PV: O^T[hd][q] += V^T x P^T, 2-stage rotating V buffer (prefetch hb+1)
#pragma unroll
    for (int hb = 0; hb < 4; ++hb) {
      if (hb < 3) {
        const bf16_t* vr =
            vbase + ((size_t)(kvb >> 4) * CHD + (hb + 1) * 32 + l31) * 16 + hi * 8;
#pragma unroll
        for (int ks = 0; ks < 4; ++ks)
          av[(hb + 1) & 1][ks] = *(const bf16x8*)(vr + (size_t)ks * CHD * 16);
      }
#pragma unroll
      for (int ks = 0; ks < 4; ++ks)
        o_[hb] = __builtin_amdgcn_mfma_f32_32x32x16_bf16(av[hb & 1][ks], pb[ks],
                                                         o_[hb], 0, 0, 0);
    }
  }

  // ---- end-of-block merge of the two kv-halves (R11-verified) ----
  if (wh == 1) {
#pragma unroll
    for (int hb = 0; hb < 4; ++hb)
#pragma unroll
      for (int r = 0; r < 16; ++r) {
        const int hd = 32 * hb + 4 * hi + (r & 3) + 8 * (r >> 2);
        Os[l31][hd] = o_[hb][r];
      }
    if (hi == 0) { Ms[l31] = m_; Ls[l31] = l_; }
  }
  __builtin_amdgcn_s_barrier();
  if (wh == 1) return;

  const float m1 = Ms[l31], l1 = Ls[l31];
  const float mn = fmaxf(m_, m1);
  const float c0 = fexp2(m_ - mn), c1 = fexp2(m1 - mn);
  const float linv = 1.0f / (l_ * c0 + l1 * c1);
  bf16_t* orow = ob + ((size_t)(b * CS + qrow)) * CH + nh * CHD;
#pragma unroll
  for (int hb = 0; hb < 4; ++hb)
#pragma unroll
    for (int g = 0; g < 4; ++g) {
      const int hd0 = 32 * hb + 4 * hi + 8 * g;
      bf16x4v pv = {
          (bf16_t)((o_[hb][4 * g + 0] * c0 + Os[l31][hd0 + 0] * c1) * linv),
          (bf16_t)((o_[hb][4 * g + 1] * c0 + Os[l31][hd0 + 1] * c1) * linv),
          (bf16_t)((o_[hb][4 * g + 2] * c0 + Os[l31][hd0 + 2] * c1) * linv),
          (bf16_t)((o_[hb][4 * g + 3] * c0 + Os[l31][hd0 + 3] * c1) * linv)};
      *(bf16x4v*)(orow + hd0) = pv;
    }
}

extern "C" void kernel_launch(void* const* d_in, const int* in_sizes, int n_in,
                              void* d_out, int out_size, void* d_ws, size_t ws_size,
                              hipStream_t stream) {
  const float* x    = (const float*)d_in[0];
  const float* cosd = (const float*)d_in[1];
  const float* sind = (const float*)d_in[2];
  // d_in[3] = mask (causal, hardcoded)
  const float* Wq = (const float*)d_in[4];
  const float* Wk = (const float*)d_in[5];
  const float* Wv = (const float*)d_in[6];
  const float* Wo = (const float*)d_in[7];

  float* yout = (float*)d_out;
  float* kout = yout + (size_t)CM * CH;
  float* vout = kout + (size_t)CM * CH;

  char* ws = (char*)d_ws;
  size_t off = 0;
  auto wsalloc = [&](size_t bytes) {
    void* p = ws + off;
    off += (bytes + 255) & ~(size_t)255;
    return p;
  };
  bf16_t* xb   = (bf16_t*)wsalloc((size_t)CM * CH * 2);
  bf16_t* wqb  = (bf16_t*)wsalloc((size_t)CH * CH * 2);
  bf16_t* wkb  = (bf16_t*)wsalloc((size_t)CH * CH * 2);
  bf16_t* wvb  = (bf16_t*)wsalloc((size_t)CH * CH * 2);
  bf16_t* wob  = (bf16_t*)wsalloc((size_t)CH * CH * 2);
  bf16_t* qraw = (bf16_t*)wsalloc((size_t)CM * CH * 2);  // Q row-major (pre-RoPE)
  bf16_t* knat = (bf16_t*)wsalloc((size_t)CM * CH * 2);  // K native (RoPE in place)
  bf16_t* vt2  = (bf16_t*)wsalloc((size_t)CM * CH * 2);  // V^T native
  bf16_t* ob   = (bf16_t*)wsalloc((size_t)CM * CH * 2);  // attn out (B*S, H)

  cvt_all<<<(CM * CH / 4 + 4 * CH * CH / 4) / 256, 256, 0, stream>>>(
      x, Wq, Wk, Wv, Wo, xb, wqb, wkb, wvb, wob);

  qkv_gemm<<<dim3(CM / 256, CH / 256, 3), 512, 0, stream>>>(xb, wqb, wkb, wvb,
                                                            qraw, knat, vt2, vout);
  rope_k<<<CB * CNH * CS * 8 / 256, 256, 0, stream>>>(knat, cosd, sind, kout);
  attn_kernel<<<CB * CNH * (CS / 32), 128, 0, stream>>>(qraw, knat, vt2, cosd,
                                                        sind, ob);
  y_gemm<<<dim3(CM / 256, CH / 256), 512, 0, stream>>>(ob, wob, yout);
}

// Round 21
// 504.089 us; speedup vs baseline: 1.2330x; 1.2330x over previous
//
#include <hip/hip_runtime.h>
#include <hip/hip_bf16.h>
#include <math.h>

typedef __bf16 bf16_t;
typedef __bf16 bf16x8 __attribute__((ext_vector_type(8)));
typedef __bf16 bf16x4v __attribute__((ext_vector_type(4)));
typedef float  f32x4  __attribute__((ext_vector_type(4)));
typedef float  f32x16 __attribute__((ext_vector_type(16)));
typedef unsigned int u32x4 __attribute__((ext_vector_type(4)));

constexpr int CB = 4, CS = 2048, CH = 2048, CNH = 16, CHD = 128;
constexpr int CM = CB * CS;  // 8192 rows of x
constexpr float CSCALE = 0.08838834764831845f;  // 128^-0.5
constexpr float CL2E   = 1.4426950408889634f;
constexpr float CSC2   = CSCALE * CL2E;         // score -> log2 domain in one mul

// raw v_exp_f32 (2^x)
__device__ __forceinline__ float fexp2(float x) {
  float r;
  asm("v_exp_f32 %0, %1" : "=v"(r) : "v"(x));
  return r;
}

// async global->LDS, 16B per lane. LDS dest is wave-uniform base (+lane*16 by HW).
__device__ __forceinline__ void g2l16(const void* g, void* l) {
  __builtin_amdgcn_global_load_lds(
      (const __attribute__((address_space(1))) void*)g,
      (__attribute__((address_space(3))) void*)l, 16, 0, 0);
}

// ---------------- f32 -> bf16 conversion: all 5 tensors in ONE launch ----------------
__global__ __launch_bounds__(256) void cvt_all(const float* __restrict__ x,
                                               const float* __restrict__ Wq,
                                               const float* __restrict__ Wk,
                                               const float* __restrict__ Wv,
                                               const float* __restrict__ Wo,
                                               bf16_t* __restrict__ xb,
                                               bf16_t* __restrict__ wqb,
                                               bf16_t* __restrict__ wkb,
                                               bf16_t* __restrict__ wvb,
                                               bf16_t* __restrict__ wob) {
  constexpr int NX = CM * CH / 4;  // float4 units in x
  constexpr int NW = CH * CH / 4;  // float4 units per weight
  const int i = blockIdx.x * 256 + threadIdx.x;
  const float* src;
  bf16_t* dst;
  int off;
  if (i < NX) {
    src = x; dst = xb; off = i;
  } else {
    const int j = i - NX;
    const int sel = j / NW;
    off = j - sel * NW;
    src = (sel == 0) ? Wq : (sel == 1) ? Wk : (sel == 2) ? Wv : Wo;
    dst = (sel == 0) ? wqb : (sel == 1) ? wkb : (sel == 2) ? wvb : wob;
  }
  float4 v = reinterpret_cast<const float4*>(src)[off];
  bf16x4v o = {(bf16_t)v.x, (bf16_t)v.y, (bf16_t)v.z, (bf16_t)v.w};
  reinterpret_cast<bf16x4v*>(dst)[off] = o;
}

// ================= 256x256 BK=64 double-buffered 4-phase GEMM =================
// (R14 version — best measured)
__device__ __forceinline__ void gemm256sq_core(const bf16_t* __restrict__ A,
                                               const bf16_t* __restrict__ Bm,
                                               bf16_t (*As2)[4][64 * 64],
                                               bf16_t (*Bs2)[4][64 * 64],
                                               int row0, int col0,
                                               f32x4 (&acc)[8][4]) {
  const int tid = threadIdx.x, lane = tid & 63, w = tid >> 6;
  const int wm = w >> 2, wn = w & 3;
  constexpr int NKT = CH / 64;  // 32 K-tiles
  const int id = w * 64 + lane;           // 0..511
  const int rl = id >> 3, ck = id & 7;    // row-local 0..63, chunk 0..7

  auto stA = [&](int buf, int kt, int q) {
    const int row = q * 64 + rl;
    g2l16(A + (size_t)(row0 + row) * CH + kt * 64 + ((ck ^ (row & 7)) << 3),
          &As2[buf][q][id * 8]);
  };
  auto stB = [&](int buf, int kt, int q) {
    const int row = q * 64 + rl;
    g2l16(Bm + (size_t)(col0 + row) * CH + kt * 64 + ((ck ^ (row & 7)) << 3),
          &Bs2[buf][q][id * 8]);
  };
  auto rdA = [&](int buf, int r, int c) -> bf16x8 {  // r: tile row 0..255
    return *(const bf16x8*)(&As2[buf][r >> 6][(r & 63) * 64 + ((c ^ (r & 7)) << 3)]);
  };
  auto rdB = [&](int buf, int r, int c) -> bf16x8 {
    return *(const bf16x8*)(&Bs2[buf][r >> 6][(r & 63) * 64 + ((c ^ (r & 7)) << 3)]);
  };

  // prologue: stage all 8 quarters of tile 0, drain, barrier
#pragma unroll
  for (int q = 0; q < 4; ++q) stB(0, 0, q);
#pragma unroll
  for (int q = 0; q < 4; ++q) stA(0, 0, q);
  asm volatile("s_waitcnt vmcnt(0)" ::: "memory");
  __builtin_amdgcn_s_barrier();
  __builtin_amdgcn_sched_barrier(0);

  const int ar0 = wm * 128 + (lane & 15);
  const int br0 = wn * 64 + (lane & 15);
  const int chi = lane >> 4;  // K-slice kk -> chunk kk*4+chi

  for (int t = 0; t < NKT; ++t) {
    const int buf = t & 1, nbuf = buf ^ 1;
    const bool pf = (t + 1 < NKT);
    bf16x8 bb[4][2], aa[2][2];

#pragma unroll
    for (int p = 0; p < 4; ++p) {
      if (p == 0) {
#pragma unroll
        for (int nf = 0; nf < 4; ++nf)
#pragma unroll
          for (int kk = 0; kk < 2; ++kk)
            bb[nf][kk] = rdB(buf, br0 + nf * 16, kk * 4 + chi);
      }
#pragma unroll
      for (int i = 0; i < 2; ++i)
#pragma unroll
        for (int kk = 0; kk < 2; ++kk)
          aa[i][kk] = rdA(buf, ar0 + (2 * p + i) * 16, kk * 4 + chi);

      if (pf) {
        if (p == 0) { stB(nbuf, t + 1, 0); stB(nbuf, t + 1, 1); }
        if (p == 1) { stA(nbuf, t + 1, 0); stA(nbuf, t + 1, 2); }
        if (p == 2) { stB(nbuf, t + 1, 2); stB(nbuf, t + 1, 3); }
        if (p == 3) { stA(nbuf, t + 1, 1); stA(nbuf, t + 1, 3); }
      }

      __builtin_amdgcn_s_barrier();
      asm volatile("s_waitcnt lgkmcnt(0)" ::: "memory");
      __builtin_amdgcn_sched_barrier(0);
      __builtin_amdgcn_s_setprio(1);
#pragma unroll
      for (int i = 0; i < 2; ++i)
#pragma unroll
        for (int nf = 0; nf < 4; ++nf)
#pragma unroll
          for (int kk = 0; kk < 2; ++kk)
            acc[2 * p + i][nf] = __builtin_amdgcn_mfma_f32_16x16x32_bf16(
                aa[i][kk], bb[nf][kk], acc[2 * p + i][nf], 0, 0, 0);
      __builtin_amdgcn_s_setprio(0);

      if (p == 1) {
        if (pf) { asm volatile("s_waitcnt vmcnt(4)" ::: "memory"); }
        else    { asm volatile("s_waitcnt vmcnt(0)" ::: "memory"); }
      }
      if (p == 3 && pf) { asm volatile("s_waitcnt vmcnt(2)" ::: "memory"); }
      __builtin_amdgcn_s_barrier();
      __builtin_amdgcn_sched_barrier(0);
    }
  }
}

// ---------------- QKV projection (grid.z selects Q/K/V; R16 version) ----------------
__global__ __launch_bounds__(512, 1) void qkv_gemm(const bf16_t* __restrict__ xb,
                                                   const bf16_t* __restrict__ wqb,
                                                   const bf16_t* __restrict__ wkb,
                                                   const bf16_t* __restrict__ wvb,
                                                   bf16_t* __restrict__ qraw,
                                                   bf16_t* __restrict__ knat,
                                                   bf16_t* __restrict__ vt2,
                                                   float* __restrict__ vout) {
  __shared__ __align__(16) bf16_t LSD[2][2][4][64 * 64];  // 128KB; [0]=A, [1]=B
  const int z = blockIdx.z;
  const bf16_t* Bm = (z == 0) ? wqb : ((z == 1) ? wkb : wvb);
  const int row0 = blockIdx.x * 256, col0 = blockIdx.y * 256;
  f32x4 acc[8][4] = {};
  gemm256sq_core(xb, Bm, LSD[0], LSD[1], row0, col0, acc);

  const int tid = threadIdx.x, lane = tid & 63, w = tid >> 6;
  const int wm = w >> 2, wn = w & 3;

  // ---- stage acc -> LDS [256][256] bf16, chunk-swizzled (ch ^= row&31) ----
  bf16_t* L = &LSD[0][0][0][0];
#pragma unroll
  for (int i = 0; i < 8; ++i)
#pragma unroll
    for (int j = 0; j < 4; ++j) {
      const int col = wn * 64 + j * 16 + (lane & 15);
#pragma unroll
      for (int r = 0; r < 4; ++r) {
        const int row = wm * 128 + i * 16 + (lane >> 4) * 4 + r;
        L[row * 256 + (((col >> 3) ^ (row & 31)) << 3) + (col & 7)] =
            (bf16_t)acc[i][j][r];
      }
    }
  if (z == 2) {
    // V^T native stores directly from acc (8B-contiguous)
#pragma unroll
    for (int i = 0; i < 8; ++i)
#pragma unroll
      for (int j = 0; j < 4; ++j) {
        const int gr0 = row0 + wm * 128 + i * 16 + (lane >> 4) * 4;
        const int gc = col0 + wn * 64 + j * 16 + (lane & 15);
        const int b = gr0 >> 11, s0 = gr0 & (CS - 1);
        const int nh = gc >> 7, hd = gc & (CHD - 1);
        const int bh = b * CNH + nh;
        bf16x4v pv = {(bf16_t)acc[i][j][0], (bf16_t)acc[i][j][1],
                      (bf16_t)acc[i][j][2], (bf16_t)acc[i][j][3]};
        *(bf16x4v*)(vt2 + (((size_t)bh * (CS / 16) + (s0 >> 4)) * CHD + hd) * 16 +
                    (s0 & 15)) = pv;
      }
  }
  __syncthreads();

  if (z == 0) {
    // Q row-major (pre-RoPE): coalesced 16B stores
#pragma unroll
    for (int k = 0; k < 16; ++k) {
      const int u = k * 512 + tid;
      const int row = u >> 5, ch = u & 31;
      bf16x8 v = *(const bf16x8*)&L[row * 256 + ((ch ^ (row & 31)) << 3)];
      const int gr = row0 + row, gc = col0 + ch * 8;
      const int b = gr >> 11, s = gr & (CS - 1), nh = gc >> 7, hd = gc & (CHD - 1);
      *(bf16x8*)&qraw[((size_t)(b * CNH + nh) * CS + s) * CHD + hd] = v;
    }
  } else if (z == 2) {
    // vout f32: row-major pass, fully-coalesced 32B per lane
#pragma unroll
    for (int k = 0; k < 16; ++k) {
      const int u = k * 512 + tid;
      const int row = u >> 5, ch = u & 31;
      bf16x8 v = *(const bf16x8*)&L[row * 256 + ((ch ^ (row & 31)) << 3)];
      const int gr = row0 + row, gc = col0 + ch * 8;
      const int b = gr >> 11, s = gr & (CS - 1), nh = gc >> 7, hd = gc & (CHD - 1);
      float o[8];
#pragma unroll
      for (int e = 0; e < 8; ++e) o[e] = (float)v[e];
      float* vp = vout + ((size_t)(b * CNH + nh) * CS + s) * CHD + hd;
      *(float4*)(vp)     = *(float4*)(o);
      *(float4*)(vp + 4) = *(float4*)(o + 4);
    }
  } else {
    // K native [bh][pan][s][16] PRE-RoPE: s-major -> 16B stores (R12-proven)
#pragma unroll
    for (int k = 0; k < 16; ++k) {
      const int u = k * 512 + tid;
      const int s = u & 255, cc = u >> 8;
      bf16x8 v = *(const bf16x8*)&L[s * 256 + ((cc ^ (s & 31)) << 3)];
      const int gr = row0 + s, gc = col0 + cc * 8;
      const int b = gr >> 11, sg = gr & (CS - 1), nh = gc >> 7, hd = gc & (CHD - 1);
      const int pan = hd >> 4, half = (hd >> 3) & 1;
      *(bf16x8*)&knat[(((size_t)(b * CNH + nh) * 8 + pan) * CS + sg) * 16 +
                      half * 8] = v;
    }
  }
}

// ---------------- output projection y = ob * Wo^T (R14 version) ----------------
__global__ __launch_bounds__(512, 1) void y_gemm(const bf16_t* __restrict__ ob,
                                                 const bf16_t* __restrict__ wob,
                                                 float* __restrict__ yout) {
  __shared__ __align__(16) bf16_t LSD[2][2][4][64 * 64];  // 128KB
  const int row0 = blockIdx.x * 256, col0 = blockIdx.y * 256;
  f32x4 acc[8][4] = {};
  gemm256sq_core(ob, wob, LSD[0], LSD[1], row0, col0, acc);
  const int tid = threadIdx.x, lane = tid & 63, w = tid >> 6;
  const int wm = w >> 2, wn = w & 3;
  float* Lf = (float*)&LSD[0][0][0][0];  // [128][256] f32 per pass

#pragma unroll
  for (int half = 0; half < 2; ++half) {
    if (wm == half) {
#pragma unroll
      for (int i = 0; i < 8; ++i)
#pragma unroll
        for (int j = 0; j < 4; ++j) {
          const int col = wn * 64 + j * 16 + (lane & 15);
#pragma unroll
          for (int r = 0; r < 4; ++r) {
            const int rl = i * 16 + (lane >> 4) * 4 + r;  // row within half
            Lf[rl * 256 + col] = acc[i][j][r];
          }
        }
    }
    __syncthreads();
#pragma unroll
    for (int k = 0; k < 16; ++k) {
      const int u = k * 512 + tid;
      const int rl = u >> 6, ch = u & 63;
      float4 v = *(const float4*)&Lf[rl * 256 + ch * 4];
      const int gr = row0 + half * 128 + rl, gc = col0 + ch * 4;
      *(float4*)&yout[(size_t)gr * CH + gc] = v;
    }
    __syncthreads();
  }
}

// ---------------- RoPE: K only (native layout, in place) + f32 kout ----------------
__global__ __launch_bounds__(256) void rope_k(bf16_t* __restrict__ knat,
                                              const float* __restrict__ cosd,
                                              const float* __restrict__ sind,
                                              float* __restrict__ kout) {
  const int gid = blockIdx.x * 256 + threadIdx.x;  // B*NH*S*8 units
  const int row = gid >> 3, sub = gid & 7;
  const int pan = sub >> 1, hf = (sub & 1) * 8;  // hd1 = pan*16+hf+e (<64)
  const int bh = row >> 11, s = row & (CS - 1);
  const int d0 = pan * 16 + hf;
  bf16_t* k1 = knat + (((size_t)bh * 8 + pan) * CS + s) * 16 + hf;
  bf16_t* k2 = knat + (((size_t)bh * 8 + pan + 4) * CS + s) * 16 + hf;
  bf16x8 v1 = *(bf16x8*)k1;
  bf16x8 v2 = *(bf16x8*)k2;
  float c[8], sn[8];
  *(float4*)(c)      = *(const float4*)(cosd + s * CHD + d0);
  *(float4*)(c + 4)  = *(const float4*)(cosd + s * CHD + d0 + 4);
  *(float4*)(sn)     = *(const float4*)(sind + s * CHD + d0);
  *(float4*)(sn + 4) = *(const float4*)(sind + s * CHD + d0 + 4);
  float f1[8], f2[8];
  bf16x8 o1, o2;
#pragma unroll
  for (int i = 0; i < 8; ++i) {
    const float x1 = (float)v1[i], x2 = (float)v2[i];
    f1[i] = x1 * c[i] - x2 * sn[i];
    f2[i] = x2 * c[i] + x1 * sn[i];
    o1[i] = (bf16_t)f1[i];
    o2[i] = (bf16_t)f2[i];
  }
  *(bf16x8*)k1 = o1;
  *(bf16x8*)k2 = o2;
  const size_t kb = (size_t)row * CHD + d0;
  *(float4*)(kout + kb)          = *(float4*)(f1);
  *(float4*)(kout + kb + 4)      = *(float4*)(f1 + 4);
  *(float4*)(kout + kb + 64)     = *(float4*)(f2);
  *(float4*)(kout + kb + 64 + 4) = *(float4*)(f2 + 4);
}

// ---------------- flash attention (R17 version — best measured) ----------------
__global__ __launch_bounds__(128, 3) void attn_kernel(const bf16_t* __restrict__ qb,
                                                      const bf16_t* __restrict__ kn,
                                                      const bf16_t* __restrict__ v2,
                                                      const float* __restrict__ cosd,
                                                      const float* __restrict__ sind,
                                                      bf16_t* __restrict__ ob) {
  __shared__ float Os[32][129];
  __shared__ float Ms[32], Ls[32];
  const int tid = threadIdx.x, lane = tid & 63, wh = tid >> 6;  // wh = kv-half
  const int hi = lane >> 5, l31 = lane & 31;

  const int swz = (blockIdx.x & 7) * 512 + (blockIdx.x >> 3);
  const int bh = swz >> 6;
  const int qt = 63 - (swz & 63);

  const int b = bh >> 4, nh = bh & (CNH - 1);
  const bf16_t* kbase = kn + (size_t)bh * 8 * CS * 16;           // [8][S][16]
  const bf16_t* vbase = v2 + (size_t)bh * (CS / 16) * CHD * 16;  // [S/16][hd][16]
  const int qw0 = qt * 32;
  const int qrow = qw0 + l31;

  // Q load + fused RoPE: frag pair (ks, ks+4) is the (d, d+64) rotation pair
  bf16x8 bq[8];
  {
    const bf16_t* qp = qb + ((size_t)bh * CS + qrow) * CHD + hi * 8;
    bf16x8 raw[8];
#pragma unroll
    for (int ks = 0; ks < 8; ++ks) raw[ks] = *(const bf16x8*)(qp + ks * 16);
#pragma unroll
    for (int p = 0; p < 4; ++p) {
      const int d0 = p * 16 + hi * 8;
      float cc[8], ss[8];
      *(float4*)(cc)     = *(const float4*)(cosd + (size_t)qrow * CHD + d0);
      *(float4*)(cc + 4) = *(const float4*)(cosd + (size_t)qrow * CHD + d0 + 4);
      *(float4*)(ss)     = *(const float4*)(sind + (size_t)qrow * CHD + d0);
      *(float4*)(ss + 4) = *(const float4*)(sind + (size_t)qrow * CHD + d0 + 4);
#pragma unroll
      for (int e = 0; e < 8; ++e) {
        const float x1 = (float)raw[p][e], x2 = (float)raw[p + 4][e];
        bq[p][e]     = (bf16_t)(x1 * cc[e] - x2 * ss[e]);
        bq[p + 4][e] = (bf16_t)(x2 * cc[e] + x1 * ss[e]);
      }
    }
  }

  float m_ = -INFINITY, l_ = 0.f;
  f32x16 o_[4] = {};  // O^T: hd = 32*hb + 4*hi + (r&3) + 8*(r>>2), q = l31

  const int nt = (qt >> 1) + 1;
  for (int kt = wh; kt < nt; kt += 2) {
    const int kvb = kt * 64;

    // QK^T swapped, K consumed in 2 batches of 8 loads (liveness 32 VGPR)
    f32x16 st[2] = {};
#pragma unroll
    for (int kb2 = 0; kb2 < 2; ++kb2) {
      bf16x8 ak[8];
      const bf16_t* kr = kbase + (size_t)(kvb + kb2 * 32 + l31) * 16 + hi * 8;
#pragma unroll
      for (int ks = 0; ks < 8; ++ks)
        ak[ks] = *(const bf16x8*)(kr + (size_t)ks * CS * 16);
#pragma unroll
      for (int ks = 0; ks < 8; ++ks)
        st[kb2] = __builtin_amdgcn_mfma_f32_32x32x16_bf16(ak[ks], bq[ks],
                                                          st[kb2], 0, 0, 0);
    }

    // scale (log2 domain) + causal mask on diagonal-crossing tiles
    const bool anymask = (kvb + 63) > qw0;
#pragma unroll
    for (int blk = 0; blk < 2; ++blk)
#pragma unroll
      for (int r = 0; r < 16; ++r) {
        float xv = st[blk][r] * CSC2;
        if (anymask) {
          const int kv = kvb + blk * 32 + 4 * hi + (r & 3) + 8 * (r >> 2);
          if (kv > qrow) xv = -INFINITY;
        }
        st[blk][r] = xv;
      }

    // row max: in-register chain + one cross-half exchange
    float tmax = st[0][0];
#pragma unroll
    for (int r = 1; r < 16; ++r) tmax = fmaxf(tmax, st[0][r]);
#pragma unroll
    for (int r = 0; r < 16; ++r) tmax = fmaxf(tmax, st[1][r]);
    tmax = fmaxf(tmax, __shfl_xor(tmax, 32, 64));

    // defer-max (T13), log2 domain: P bounded by 2^8
    if (__any(tmax - m_ > 8.0f)) {
      const float mn = fmaxf(m_, tmax);
      const float corr = fexp2(m_ - mn);
      m_ = mn;
      l_ *= corr;
#pragma unroll
      for (int hb = 0; hb < 4; ++hb) o_[hb] *= corr;
    }

    // P = exp2(x - m) in place, row sum
    float psum = 0.f;
#pragma unroll
    for (int blk = 0; blk < 2; ++blk)
#pragma unroll
      for (int r = 0; r < 16; ++r) {
        const float pv = fexp2(st[blk][r] - m_);
        st[blk][r] = pv;
        psum += pv;
      }
    psum += __shfl_xor(psum, 32, 64);
    l_ += psum;

    // preload V hb=0 (latency hides under pb conversion)
    bf16x8 av[2][4];
    {
      const bf16_t* vr = vbase + ((size_t)(kvb >> 4) * CHD + l31) * 16 + hi * 8;
#pragma unroll
      for (int ks = 0; ks < 4; ++ks)
        av[0][ks] = *(const bf16x8*)(vr + (size_t)ks * CHD * 16);
    }

    // P^T B-frags: 16 cvt_pk + 8 permlane32_swap (R9-verified pairing)
    bf16x8 pb[4];
#pragma unroll
    for (int ks = 0; ks < 4; ++ks) {
      const int blk = ks >> 1, r0 = (ks & 1) * 8;
      unsigned pw0, pw1, pw2, pw3;
      asm("v_cvt_pk_bf16_f32 %0, %1, %2" : "=v"(pw0) : "v"(st[blk][r0 + 0]), "v"(st[blk][r0 + 1]));
      asm("v_cvt_pk_bf16_f32 %0, %1, %2" : "=v"(pw2) : "v"(st[blk][r0 + 4]), "v"(st[blk][r0 + 5]));
      asm("v_cvt_pk_bf16_f32 %0, %1, %2" : "=v"(pw1) : "v"(st[blk][r0 + 2]), "v"(st[blk][r0 + 3]));
      asm("v_cvt_pk_bf16_f32 %0, %1, %2" : "=v"(pw3) : "v"(st[blk][r0 + 6]), "v"(st[blk][r0 + 7]));
      asm("v_permlane32_swap_b32 %0, %1" : "+v"(pw0), "+v"(pw2));
      asm("v_permlane32_swap_b32 %0, %1" : "+v"(pw1), "+v"(pw3));
      u32x4 pk = {pw0, pw1, pw2, pw3};
      pb[ks] = *reinterpret_cast<bf16x8*>(&pk);
    }

    // PV: O^T[hd][q] += V^T x P^T, 2-stage rotating V buffer (prefetch hb+1)
#pragma unroll
    for (int hb = 0; hb < 4; ++hb) {
      if (hb < 3) {
        const bf16_t* vr =
            vbase + ((size_t)(kvb >> 4) * CHD + (hb + 1) * 32 + l31) * 16 + hi * 8;
#pragma unroll
        for (int ks = 0; ks < 4; ++ks)
          av[(hb + 1) & 1][ks] = *(const bf16x8*)(vr + (size_t)ks * CHD * 16);
      }
#pragma unroll
      for (int ks = 0; ks < 4; ++ks)
        o_[hb] = __builtin_amdgcn_mfma_f32_32x32x16_bf16(av[hb & 1][ks], pb[ks],
                                                         o_[hb], 0, 0, 0);
    }
  }

  // ---- end-of-block merge of the two kv-halves (R11-verified) ----
  if (wh == 1) {
#pragma unroll
    for (int hb = 0; hb < 4; ++hb)
#pragma unroll
      for (int r = 0; r < 16; ++r) {
        const int hd = 32 * hb + 4 * hi + (r & 3) + 8 * (r >> 2);
        Os[l31][hd] = o_[hb][r];
      }
    if (hi == 0) { Ms[l31] = m_; Ls[l31] = l_; }
  }
  __builtin_amdgcn_s_barrier();
  if (wh == 1) return;

  const float m1 = Ms[l31], l1 = Ls[l31];
  const float mn = fmaxf(m_, m1);
  const float c0 = fexp2(m_ - mn), c1 = fexp2(m1 - mn);
  const float linv = 1.0f / (l_ * c0 + l1 * c1);
  bf16_t* orow = ob + ((size_t)(b * CS + qrow)) * CH + nh * CHD;
#pragma unroll
  for (int hb = 0; hb < 4; ++hb)
#pragma unroll
    for (int g = 0; g < 4; ++g) {
      const int hd0 = 32 * hb + 4 * hi + 8 * g;
      bf16x4v pv = {
          (bf16_t)((o_[hb][4 * g + 0] * c0 + Os[l31][hd0 + 0] * c1) * linv),
          (bf16_t)((o_[hb][4 * g + 1] * c0 + Os[l31][hd0 + 1] * c1) * linv),
          (bf16_t)((o_[hb][4 * g + 2] * c0 + Os[l31][hd0 + 2] * c1) * linv),
          (bf16_t)((o_[hb][4 * g + 3] * c0 + Os[l31][hd0 + 3] * c1) * linv)};
      *(bf16x4v*)(orow + hd0) = pv;
    }
}

extern "C" void kernel_launch(void* const* d_in, const int* in_sizes, int n_in,
                              void* d_out, int out_size, void* d_ws, size_t ws_size,
                              hipStream_t stream) {
  const float* x    = (const float*)d_in[0];
  const float* cosd = (const float*)d_in[1];
  const float* sind = (const float*)d_in[2];
  // d_in[3] = mask (causal, hardcoded)
  const float* Wq = (const float*)d_in[4];
  const float* Wk = (const float*)d_in[5];
  const float* Wv = (const float*)d_in[6];
  const float* Wo = (const float*)d_in[7];

  float* yout = (float*)d_out;
  float* kout = yout + (size_t)CM * CH;
  float* vout = kout + (size_t)CM * CH;

  char* ws = (char*)d_ws;
  size_t off = 0;
  auto wsalloc = [&](size_t bytes) {
    void* p = ws + off;
    off += (bytes + 255) & ~(size_t)255;
    return p;
  };
  bf16_t* xb   = (bf16_t*)wsalloc((size_t)CM * CH * 2);
  bf16_t* wqb  = (bf16_t*)wsalloc((size_t)CH * CH * 2);
  bf16_t* wkb  = (bf16_t*)wsalloc((size_t)CH * CH * 2);
  bf16_t* wvb  = (bf16_t*)wsalloc((size_t)CH * CH * 2);
  bf16_t* wob  = (bf16_t*)wsalloc((size_t)CH * CH * 2);
  bf16_t* qraw = (bf16_t*)wsalloc((size_t)CM * CH * 2);  // Q row-major (pre-RoPE)
  bf16_t* knat = (bf16_t*)wsalloc((size_t)CM * CH * 2);  // K native (RoPE in place)
  bf16_t* vt2  = (bf16_t*)wsalloc((size_t)CM * CH * 2);  // V^T native
  bf16_t* ob   = (bf16_t*)wsalloc((size_t)CM * CH * 2);  // attn out (B*S, H)

  cvt_all<<<(CM * CH / 4 + 4 * CH * CH / 4) / 256, 256, 0, stream>>>(
      x, Wq, Wk, Wv, Wo, xb, wqb, wkb, wvb, wob);

  qkv_gemm<<<dim3(CM / 256, CH / 256, 3), 512, 0, stream>>>(xb, wqb, wkb, wvb,
                                                            qraw, knat, vt2, vout);
  rope_k<<<CB * CNH * CS * 8 / 256, 256, 0, stream>>>(knat, cosd, sind, kout);
  attn_kernel<<<CB * CNH * (CS / 32), 128, 0, stream>>>(qraw, knat, vt2, cosd,
                                                        sind, ob);
  y_gemm<<<dim3(CM / 256, CH / 256), 512, 0, stream>>>(ob, wob, yout);
}